// Round 11
// baseline (442.701 us; speedup 1.0000x reference)
//
#include <hip/hip_runtime.h>

// ---------------------------------------------------------------------------
// Attention_17703855194398: AdaRMSNorm -> QKV -> per-head RMS+RoPE -> SDPA -> out
// B=2, L=2048, D=2048, NH=32, HD=64, DC=2048
// R14: QKV split for perfect grid balance (R13 post-mortem: 384 blocks at
//      1 block/CU = 1.5 rounds, aggregate 911 TF vs 1224 TF full-round rate):
//      - qk: 256x256 8-phase, N=4096 -> grid 256 = exactly 1 round.
//      - v : 256x128 4-phase, N=2048 -> grid 256 = exactly 1 round,
//            Vt-scatter epilogue.
//      ada_gemm + cast2 merged into prep_kernel (independent; keeps 7 launches).
//      attn / rope / out-proj / ada_rms unchanged (all verified).
// ---------------------------------------------------------------------------

typedef __bf16 bf16x8 __attribute__((ext_vector_type(8)));
typedef float  f32x4  __attribute__((ext_vector_type(4)));
typedef float  f32x16 __attribute__((ext_vector_type(16)));

#define EPS_F32 1.1920929e-07f
// q prescale: (1/sqrt(64)) * log2(e)  -> scores land in exp2 domain
#define QSCALE 0.18033688011112042f

#if defined(__has_builtin)
#  if __has_builtin(__builtin_amdgcn_exp2f)
#    define EXP2F(x) __builtin_amdgcn_exp2f(x)
#  else
#    define EXP2F(x) __expf((x) * 0.6931471805599453f)
#  endif
#  if __has_builtin(__builtin_amdgcn_rcpf)
#    define RCPF(x) __builtin_amdgcn_rcpf(x)
#  else
#    define RCPF(x) (1.0f / (x))
#  endif
#else
#  define EXP2F(x) __expf((x) * 0.6931471805599453f)
#  define RCPF(x) (1.0f / (x))
#endif

__device__ __forceinline__ float bf2f(unsigned int u16) {
  union { unsigned int i; float f; } v; v.i = (u16 & 0xffffu) << 16; return v.f;
}
__device__ __forceinline__ float bf2f_hi(unsigned int u32) {
  union { unsigned int i; float f; } v; v.i = u32 & 0xffff0000u; return v.f;
}
__device__ __forceinline__ unsigned short f2bf(float f) {
  union { float f; unsigned int i; } v; v.f = f;
  unsigned int r = v.i + 0x7fffu + ((v.i >> 16) & 1u);  // RNE
  return (unsigned short)(r >> 16);
}
// round-to-nearest (ties away) bf16 bits, cheap: 2 ops
__device__ __forceinline__ unsigned int f2bf_rn_u(float f) {
  union { float f; unsigned int i; } v; v.f = f;
  return v.i + 0x8000u;   // caller takes >>16 or &0xffff0000
}

// async global->LDS, 16B per lane (wave-uniform base + lane*16)
__device__ __forceinline__ void gload16(const void* g, void* l) {
  __builtin_amdgcn_global_load_lds(
      (const __attribute__((address_space(1))) unsigned int*)(unsigned long long)g,
      (__attribute__((address_space(3))) unsigned int*)(unsigned int)(unsigned long long)l,
      16, 0, 0);
}

// ---------------------------------------------------------------------------
// 1) prep: blocks 0..2047 = ada GEMM (ss[b,j] = cond[b,:]·w_ada[j,:]);
//          blocks 2048..18431 = fp32->bf16 weight cast (w_qkv then w_out,
//          contiguous dst). Independent work merged to save a launch gap.
// ---------------------------------------------------------------------------
__global__ __launch_bounds__(256) void prep_kernel(
    const float* __restrict__ cond, const float* __restrict__ w_ada,
    float* __restrict__ ss,
    const float* __restrict__ wq_f, const float* __restrict__ wo_f,
    unsigned short* __restrict__ dst)
{
  if (blockIdx.x >= 2048) {
    const int i = (blockIdx.x - 2048) * 256 + threadIdx.x;   // 0..4194303
    float4 v = (i < 3145728) ? ((const float4*)wq_f)[i]
                             : ((const float4*)wo_f)[i - 3145728];
    unsigned int p0 = (unsigned int)f2bf(v.x) | ((unsigned int)f2bf(v.y) << 16);
    unsigned int p1 = (unsigned int)f2bf(v.z) | ((unsigned int)f2bf(v.w) << 16);
    *(uint2*)&dst[(size_t)i * 4] = make_uint2(p0, p1);
    return;
  }
  const int lane = threadIdx.x & 63;
  const int gw = blockIdx.x * 4 + (threadIdx.x >> 6);
  const int b = gw >> 12;
  const int j = gw & 4095;
  const float4* wr = (const float4*)(w_ada + j * 2048);
  const float4* cr = (const float4*)(cond + b * 2048);
  float acc = 0.f;
  #pragma unroll
  for (int k4 = 0; k4 < 8; ++k4) {
    float4 w = wr[lane + k4 * 64];
    float4 c = cr[lane + k4 * 64];
    acc += w.x * c.x + w.y * c.y + w.z * c.z + w.w * c.w;
  }
  #pragma unroll
  for (int off = 1; off < 64; off <<= 1) acc += __shfl_xor(acc, off);
  if (lane == 0) ss[b * 4096 + j] = acc;
}

// ---------------------------------------------------------------------------
// 2) AdaRMSNorm: h = rms_norm(x)*(1+scale) + shift, write bf16
// ---------------------------------------------------------------------------
__global__ __launch_bounds__(256) void ada_rms_kernel(
    const float* __restrict__ x, const float* __restrict__ ss,
    unsigned short* __restrict__ H)
{
  const int row = blockIdx.x;
  const int b = row >> 11;
  const int tid = threadIdx.x;
  const int lane = tid & 63, wave = tid >> 6;
  const float* xr = x + (size_t)row * 2048;
  float4 v0 = ((const float4*)xr)[tid * 2];
  float4 v1 = ((const float4*)xr)[tid * 2 + 1];
  float ssq = v0.x*v0.x + v0.y*v0.y + v0.z*v0.z + v0.w*v0.w
            + v1.x*v1.x + v1.y*v1.y + v1.z*v1.z + v1.w*v1.w;
  #pragma unroll
  for (int off = 1; off < 64; off <<= 1) ssq += __shfl_xor(ssq, off);
  __shared__ float red[4];
  if (lane == 0) red[wave] = ssq;
  __syncthreads();
  const float tot = red[0] + red[1] + red[2] + red[3];
  const float r = rsqrtf(tot * (1.f / 2048.f) + EPS_F32);
  const int c0 = tid * 8;
  const float* sh = ss + b * 4096;
  float xv[8] = {v0.x, v0.y, v0.z, v0.w, v1.x, v1.y, v1.z, v1.w};
  unsigned int pk[4];
  #pragma unroll
  for (int p = 0; p < 4; ++p) {
    const int c = c0 + p * 2;
    float h0 = xv[p*2+0] * r * (1.f + sh[2048 + c])     + sh[c];
    float h1 = xv[p*2+1] * r * (1.f + sh[2048 + c + 1]) + sh[c + 1];
    pk[p] = (unsigned int)f2bf(h0) | ((unsigned int)f2bf(h1) << 16);
  }
  *(uint4*)&H[(size_t)row * 2048 + c0] = make_uint4(pk[0], pk[1], pk[2], pk[3]);
}

// ---------------------------------------------------------------------------
// 3a) qk GEMM: 256x256 tile, BK=64, 8-phase schedule (8 waves = 2M x 4N).
//    M=4096, N=4096 (q,k cols of w_qkv), K=2048. grid 256 = 1 full round.
//    C stride stays 6144 (writes into the QKV buffer's first 4096 cols).
// ---------------------------------------------------------------------------
__global__ __launch_bounds__(512, 2) void gemm_qk_8p(
    const unsigned short* __restrict__ A,
    const unsigned short* __restrict__ Bw,
    unsigned short* __restrict__ C)
{
  __shared__ unsigned short As[2][2][8192];   // [buf][khalf][256 rows * 32 k]
  __shared__ unsigned short Bs[2][2][8192];

  const int tid  = threadIdx.x;
  const int lane = tid & 63;
  const int wave = tid >> 6;              // 0..7
  const int wrow = (wave >> 2) * 128;     // 0 / 128
  const int wcol = (wave & 3) * 64;       // 0 / 64 / 128 / 192

  // bijective XCD chunk swizzle (256 % 8 == 0, 32 blocks/XCD, bx-major)
  const int swz = (blockIdx.x & 7) * 32 + (blockIdx.x >> 3);
  const int bx = swz >> 4;                // 0..15  (N tiles)
  const int by = swz & 15;                // 0..15  (M tiles)
  const int bm = by * 256;
  const int bn = bx * 256;

  const int fr = lane & 15;
  const int q_ = lane >> 4;
  const int laneoff = fr * 32 + ((q_ ^ ((fr >> 1) & 3)) << 3);

  const int rA  = wave * 32 + (lane >> 2);            // j=0 row (j=1: +16)
  const int kk  = (lane & 3) ^ ((lane >> 3) & 3);     // inverse-swizzled k-octet
  const unsigned short* Ag0 = A  + (size_t)(bm + rA) * 2048 + kk * 8;
  const unsigned short* Ag1 = Ag0 + (size_t)16 * 2048;
  const unsigned short* Bg0 = Bw + (size_t)(bn + rA) * 2048 + kk * 8;
  const unsigned short* Bg1 = Bg0 + (size_t)16 * 2048;
  const int ldso = rA * 32 + (lane & 3) * 8;          // linear LDS dest (j=1: +512)

  f32x4 acc[8][4] = {};
  bf16x8 fA[4], fB[4];

#define STAGE_A(SB, SKH, KT) do { \
    gload16(Ag0 + (KT) * 64 + (SKH) * 32, &As[SB][SKH][ldso]); \
    gload16(Ag1 + (KT) * 64 + (SKH) * 32, &As[SB][SKH][ldso + 512]); } while (0)
#define STAGE_B(SB, SKH, KT) do { \
    gload16(Bg0 + (KT) * 64 + (SKH) * 32, &Bs[SB][SKH][ldso]); \
    gload16(Bg1 + (KT) * 64 + (SKH) * 32, &Bs[SB][SKH][ldso + 512]); } while (0)
#define VMW(N) asm volatile("s_waitcnt vmcnt(" #N ")" ::: "memory")
#define LDB(BUF, KH) do { const unsigned short* p_ = &Bs[BUF][KH][wcol * 32 + laneoff]; \
    fB[0] = *(const bf16x8*)&p_[0];    fB[1] = *(const bf16x8*)&p_[512]; \
    fB[2] = *(const bf16x8*)&p_[1024]; fB[3] = *(const bf16x8*)&p_[1536]; } while (0)
#define LDA(BUF, KH, MH) do { const unsigned short* p_ = &As[BUF][KH][(wrow + (MH) * 64) * 32 + laneoff]; \
    fA[0] = *(const bf16x8*)&p_[0];    fA[1] = *(const bf16x8*)&p_[512]; \
    fA[2] = *(const bf16x8*)&p_[1024]; fA[3] = *(const bf16x8*)&p_[1536]; } while (0)
#define MFMA16(MH) do { \
    _Pragma("unroll") \
    for (int f_ = 0; f_ < 4; ++f_) { \
      _Pragma("unroll") \
      for (int n_ = 0; n_ < 4; ++n_) \
        acc[(MH) * 4 + f_][n_] = __builtin_amdgcn_mfma_f32_16x16x32_bf16( \
            fA[f_], fB[n_], acc[(MH) * 4 + f_][n_], 0, 0, 0); \
    } } while (0)
#define PH_MID() do { __builtin_amdgcn_s_barrier(); \
    asm volatile("s_waitcnt lgkmcnt(0)"); \
    __builtin_amdgcn_s_setprio(1); } while (0)
#define PH_END() do { __builtin_amdgcn_s_setprio(0); \
    __builtin_amdgcn_s_barrier(); } while (0)

  // prologue: stage K-tile 0 into buf0 (order Ak0, Bk0, Ak1, Bk1)
  STAGE_A(0, 0, 0); STAGE_B(0, 0, 0); STAGE_A(0, 1, 0); STAGE_B(0, 1, 0);
  VMW(4);                      // Ak0+Bk0 landed; Ak1+Bk1 still in flight
  __builtin_amdgcn_s_barrier();

  for (int it = 0; it < 16; ++it) {
    const int t1 = 2 * it + 1;
    const int t2 = 2 * it + 2;
    const bool pf = (it < 15);

    // ---- K-tile 2it (buf0); stage K-tile 2it+1 -> buf1 ----
    LDB(0, 0); LDA(0, 0, 0);
    STAGE_A(1, 0, t1);
    PH_MID(); MFMA16(0); PH_END();
    LDA(0, 0, 1);
    STAGE_B(1, 0, t1);
    VMW(4);                    // retire prev P7/P8 (buf0 Ak1,Bk1) for P3
    PH_MID(); MFMA16(1); PH_END();
    LDB(0, 1); LDA(0, 1, 0);
    STAGE_A(1, 1, t1);
    PH_MID(); MFMA16(0); PH_END();
    LDA(0, 1, 1);
    STAGE_B(1, 1, t1);
    VMW(4);                    // retire P1/P2 (buf1 Ak0,Bk0) for P5
    PH_MID(); MFMA16(1); PH_END();

    // ---- K-tile 2it+1 (buf1); stage K-tile 2it+2 -> buf0 ----
    LDB(1, 0); LDA(1, 0, 0);
    if (pf) STAGE_A(0, 0, t2);
    PH_MID(); MFMA16(0); PH_END();
    LDA(1, 0, 1);
    if (pf) { STAGE_B(0, 0, t2); VMW(4); }  // retire P3/P4 (buf1 Ak1,Bk1)
    else    { VMW(0); }                     // last iter: drain P3/P4
    PH_MID(); MFMA16(1); PH_END();
    LDB(1, 1); LDA(1, 1, 0);
    if (pf) STAGE_A(0, 1, t2);
    PH_MID(); MFMA16(0); PH_END();
    LDA(1, 1, 1);
    if (pf) STAGE_B(0, 1, t2);
    VMW(4);                    // retire P5/P6 (buf0 Ak0,Bk0) for next P1
    PH_MID(); MFMA16(1); PH_END();
  }

#undef STAGE_A
#undef STAGE_B
#undef VMW
#undef LDB
#undef LDA
#undef MFMA16
#undef PH_MID
#undef PH_END

  // epilogue: plain bf16, per-wave 128x64 block; C row stride 6144.
  const int cr = (lane >> 4) * 4;
  const int cc = lane & 15;
  #pragma unroll
  for (int mf = 0; mf < 8; ++mf)
    #pragma unroll
    for (int nf = 0; nf < 4; ++nf)
      #pragma unroll
      for (int r = 0; r < 4; ++r) {
        const int row = bm + wrow + mf * 16 + cr + r;
        const int col = bn + wcol + nf * 16 + cc;
        C[(size_t)row * 6144 + col] = f2bf(acc[mf][nf][r]);
      }
}

// ---------------------------------------------------------------------------
// 3b) v GEMM: 256x128 tile, BK=64, 4-phase schedule, 512 threads
//    (8 waves = 4M x 2N). M=4096, N=2048 (v cols), grid 256 = 1 full round.
//    Bw pre-offset to the v rows of w_qkv. Epilogue: Vt scatter
//    (transposed + k-permuted), dg is v-relative (0..2047).
// ---------------------------------------------------------------------------
__global__ __launch_bounds__(512, 1) void gemm_v_4p(
    const unsigned short* __restrict__ A,
    const unsigned short* __restrict__ Bw,   // w_qkv rows 4096..6143 (bf16)
    unsigned short* __restrict__ vt)
{
  __shared__ unsigned short As[2][2][8192];   // [buf][khalf][256 rows * 32 k]
  __shared__ unsigned short Bs[2][2][4096];   // [buf][khalf][128 rows * 32 k]

  const int tid  = threadIdx.x;
  const int lane = tid & 63;
  const int wave = tid >> 6;              // 0..7
  const int wrow = (wave >> 1) * 64;      // 0/64/128/192
  const int wcol = (wave & 1) * 64;       // 0/64

  // bijective XCD chunk swizzle (256 % 8 == 0, 32 blocks per XCD)
  const int swz = (blockIdx.x & 7) * 32 + (blockIdx.x >> 3);
  const int bx = swz >> 4;                // 0..15 (N tiles of 128)
  const int by = swz & 15;                // 0..15 (M tiles of 256)
  const int bm = by * 256;
  const int bn = bx * 128;

  const int fr = lane & 15;
  const int q_ = lane >> 4;
  const int laneoff = fr * 32 + ((q_ ^ ((fr >> 1) & 3)) << 3);

  const int rA = wave * 32 + (lane >> 2);             // A rows (2nd load: +16)
  const int rB = wave * 16 + (lane >> 2);             // B rows
  const int kk = (lane & 3) ^ ((lane >> 3) & 3);      // inverse-swizzled k-octet
  const unsigned short* Ag0 = A  + (size_t)(bm + rA) * 2048 + kk * 8;
  const unsigned short* Ag1 = Ag0 + (size_t)16 * 2048;
  const unsigned short* Bg0 = Bw + (size_t)(bn + rB) * 2048 + kk * 8;
  const int ldsoA = rA * 32 + (lane & 3) * 8;
  const int ldsoB = rB * 32 + (lane & 3) * 8;

  f32x4 acc[4][4] = {};
  bf16x8 fA[4], fB[4];

#define STAGE_A4(SB, SKH, KT) do { \
    gload16(Ag0 + (KT) * 64 + (SKH) * 32, &As[SB][SKH][ldsoA]); \
    gload16(Ag1 + (KT) * 64 + (SKH) * 32, &As[SB][SKH][ldsoA + 512]); } while (0)
#define STAGE_B4(SB, SKH, KT) \
    gload16(Bg0 + (KT) * 64 + (SKH) * 32, &Bs[SB][SKH][ldsoB])
#define VMW(N) asm volatile("s_waitcnt vmcnt(" #N ")" ::: "memory")
#define LDB4(BUF, KH) do { const unsigned short* p_ = &Bs[BUF][KH][wcol * 32 + laneoff]; \
    fB[0] = *(const bf16x8*)&p_[0];    fB[1] = *(const bf16x8*)&p_[512]; \
    fB[2] = *(const bf16x8*)&p_[1024]; fB[3] = *(const bf16x8*)&p_[1536]; } while (0)
#define LDA4(BUF, KH) do { const unsigned short* p_ = &As[BUF][KH][wrow * 32 + laneoff]; \
    fA[0] = *(const bf16x8*)&p_[0];    fA[1] = *(const bf16x8*)&p_[512]; \
    fA[2] = *(const bf16x8*)&p_[1024]; fA[3] = *(const bf16x8*)&p_[1536]; } while (0)
#define MFMA16_4() do { \
    _Pragma("unroll") \
    for (int f_ = 0; f_ < 4; ++f_) { \
      _Pragma("unroll") \
      for (int n_ = 0; n_ < 4; ++n_) \
        acc[f_][n_] = __builtin_amdgcn_mfma_f32_16x16x32_bf16( \
            fA[f_], fB[n_], acc[f_][n_], 0, 0, 0); \
    } } while (0)
#define PH_MID() do { __builtin_amdgcn_s_barrier(); \
    asm volatile("s_waitcnt lgkmcnt(0)"); \
    __builtin_amdgcn_s_setprio(1); } while (0)
#define PH_END() do { __builtin_amdgcn_s_setprio(0); \
    __builtin_amdgcn_s_barrier(); } while (0)

  // prologue: stage K-tile 0 (k0 batch: A 2 loads + B 1; then k1 batch)
  STAGE_A4(0, 0, 0); STAGE_B4(0, 0, 0);
  STAGE_A4(0, 1, 0); STAGE_B4(0, 1, 0);
  VMW(3);                      // k0 batch landed; k1 batch in flight
  __builtin_amdgcn_s_barrier();

  for (int it = 0; it < 16; ++it) {
    const int t1 = 2 * it + 1;
    const int t2 = 2 * it + 2;
    const bool pf = (it < 15);

    // ---- K-tile 2it (buf0); stage K-tile 2it+1 -> buf1 ----
    LDB4(0, 0); LDA4(0, 0);
    STAGE_A4(1, 0, t1); STAGE_B4(1, 0, t1);
    VMW(3);                    // retire prev tile's k1 batch (read next phase)
    PH_MID(); MFMA16_4(); PH_END();
    LDB4(0, 1); LDA4(0, 1);
    STAGE_A4(1, 1, t1); STAGE_B4(1, 1, t1);
    VMW(3);                    // retire buf1-k0 batch
    PH_MID(); MFMA16_4(); PH_END();

    // ---- K-tile 2it+1 (buf1); stage K-tile 2it+2 -> buf0 ----
    LDB4(1, 0); LDA4(1, 0);
    if (pf) { STAGE_A4(0, 0, t2); STAGE_B4(0, 0, t2); VMW(3); }
    else    { VMW(0); }
    PH_MID(); MFMA16_4(); PH_END();
    LDB4(1, 1); LDA4(1, 1);
    if (pf) { STAGE_A4(0, 1, t2); STAGE_B4(0, 1, t2); VMW(3); }
    else    { VMW(0); }
    PH_MID(); MFMA16_4(); PH_END();
  }

#undef STAGE_A4
#undef STAGE_B4
#undef VMW
#undef LDB4
#undef LDA4
#undef MFMA16_4
#undef PH_MID
#undef PH_END

  // epilogue: Vt scatter (transposed + k-permuted), per-wave 64x64 block
  const int cr = (lane >> 4) * 4;
  const int cc = lane & 15;
  #pragma unroll
  for (int f = 0; f < 4; ++f)
    #pragma unroll
    for (int n = 0; n < 4; ++n)
      #pragma unroll
      for (int r = 0; r < 4; ++r) {
        const int m  = bm + wrow + f * 16 + cr + r;
        const int dg = bn + wcol + n * 16 + cc;       // v-relative 0..2047
        const int l  = m & 2047;
        const size_t dst = ((size_t)((m >> 11) * 32 + (dg >> 6)) * 64 + (dg & 63)) * 2048
                         + (l >> 6) * 64 + (l & 15) * 4 + ((l >> 4) & 3);
        vt[dst] = f2bf(acc[f][n][r]);
      }
}

// ---------------------------------------------------------------------------
// 4) out-projection GEMM: 256x128 tile, BK=64, 4-phase schedule,
//    512 threads (8 waves = 4M x 2N). grid 256 = exactly 1 block/CU.
//    A = attn O [4096][2048] bf16, Bw = w_out [2048][2048] bf16, C f32.
// ---------------------------------------------------------------------------
__global__ __launch_bounds__(512, 1) void gemm_out_4p(
    const unsigned short* __restrict__ A,
    const unsigned short* __restrict__ Bw,
    float* __restrict__ C)
{
  __shared__ unsigned short As[2][2][8192];   // [buf][khalf][256 rows * 32 k]
  __shared__ unsigned short Bs[2][2][4096];   // [buf][khalf][128 rows * 32 k]

  const int tid  = threadIdx.x;
  const int lane = tid & 63;
  const int wave = tid >> 6;              // 0..7
  const int wrow = (wave >> 1) * 64;      // 0/64/128/192
  const int wcol = (wave & 1) * 64;       // 0/64

  // bijective XCD chunk swizzle (256 % 8 == 0, 32 blocks per XCD)
  const int swz = (blockIdx.x & 7) * 32 + (blockIdx.x >> 3);
  const int bx = swz >> 4;                // 0..15 (N tiles of 128)
  const int by = swz & 15;                // 0..15 (M tiles of 256)
  const int bm = by * 256;
  const int bn = bx * 128;

  const int fr = lane & 15;
  const int q_ = lane >> 4;
  const int laneoff = fr * 32 + ((q_ ^ ((fr >> 1) & 3)) << 3);

  const int rA = wave * 32 + (lane >> 2);             // A rows (2nd load: +16)
  const int rB = wave * 16 + (lane >> 2);             // B rows
  const int kk = (lane & 3) ^ ((lane >> 3) & 3);      // inverse-swizzled k-octet
  const unsigned short* Ag0 = A  + (size_t)(bm + rA) * 2048 + kk * 8;
  const unsigned short* Ag1 = Ag0 + (size_t)16 * 2048;
  const unsigned short* Bg0 = Bw + (size_t)(bn + rB) * 2048 + kk * 8;
  const int ldsoA = rA * 32 + (lane & 3) * 8;
  const int ldsoB = rB * 32 + (lane & 3) * 8;

  f32x4 acc[4][4] = {};
  bf16x8 fA[4], fB[4];

#define STAGE_A4(SB, SKH, KT) do { \
    gload16(Ag0 + (KT) * 64 + (SKH) * 32, &As[SB][SKH][ldsoA]); \
    gload16(Ag1 + (KT) * 64 + (SKH) * 32, &As[SB][SKH][ldsoA + 512]); } while (0)
#define STAGE_B4(SB, SKH, KT) \
    gload16(Bg0 + (KT) * 64 + (SKH) * 32, &Bs[SB][SKH][ldsoB])
#define VMW(N) asm volatile("s_waitcnt vmcnt(" #N ")" ::: "memory")
#define LDB4(BUF, KH) do { const unsigned short* p_ = &Bs[BUF][KH][wcol * 32 + laneoff]; \
    fB[0] = *(const bf16x8*)&p_[0];    fB[1] = *(const bf16x8*)&p_[512]; \
    fB[2] = *(const bf16x8*)&p_[1024]; fB[3] = *(const bf16x8*)&p_[1536]; } while (0)
#define LDA4(BUF, KH) do { const unsigned short* p_ = &As[BUF][KH][wrow * 32 + laneoff]; \
    fA[0] = *(const bf16x8*)&p_[0];    fA[1] = *(const bf16x8*)&p_[512]; \
    fA[2] = *(const bf16x8*)&p_[1024]; fA[3] = *(const bf16x8*)&p_[1536]; } while (0)
#define MFMA16_4() do { \
    _Pragma("unroll") \
    for (int f_ = 0; f_ < 4; ++f_) { \
      _Pragma("unroll") \
      for (int n_ = 0; n_ < 4; ++n_) \
        acc[f_][n_] = __builtin_amdgcn_mfma_f32_16x16x32_bf16( \
            fA[f_], fB[n_], acc[f_][n_], 0, 0, 0); \
    } } while (0)
#define PH_MID() do { __builtin_amdgcn_s_barrier(); \
    asm volatile("s_waitcnt lgkmcnt(0)"); \
    __builtin_amdgcn_s_setprio(1); } while (0)
#define PH_END() do { __builtin_amdgcn_s_setprio(0); \
    __builtin_amdgcn_s_barrier(); } while (0)

  // prologue: stage K-tile 0 (k0 batch: A 2 loads + B 1; then k1 batch)
  STAGE_A4(0, 0, 0); STAGE_B4(0, 0, 0);
  STAGE_A4(0, 1, 0); STAGE_B4(0, 1, 0);
  VMW(3);                      // k0 batch landed; k1 batch in flight
  __builtin_amdgcn_s_barrier();

  for (int it = 0; it < 16; ++it) {
    const int t1 = 2 * it + 1;
    const int t2 = 2 * it + 2;
    const bool pf = (it < 15);

    // ---- K-tile 2it (buf0); stage K-tile 2it+1 -> buf1 ----
    LDB4(0, 0); LDA4(0, 0);
    STAGE_A4(1, 0, t1); STAGE_B4(1, 0, t1);
    VMW(3);                    // retire prev tile's k1 batch (read next phase)
    PH_MID(); MFMA16_4(); PH_END();
    LDB4(0, 1); LDA4(0, 1);
    STAGE_A4(1, 1, t1); STAGE_B4(1, 1, t1);
    VMW(3);                    // retire buf1-k0 batch
    PH_MID(); MFMA16_4(); PH_END();

    // ---- K-tile 2it+1 (buf1); stage K-tile 2it+2 -> buf0 ----
    LDB4(1, 0); LDA4(1, 0);
    if (pf) { STAGE_A4(0, 0, t2); STAGE_B4(0, 0, t2); VMW(3); }
    else    { VMW(0); }
    PH_MID(); MFMA16_4(); PH_END();
    LDB4(1, 1); LDA4(1, 1);
    if (pf) { STAGE_A4(0, 1, t2); STAGE_B4(0, 1, t2); VMW(3); }
    else    { VMW(0); }
    PH_MID(); MFMA16_4(); PH_END();
  }

#undef STAGE_A4
#undef STAGE_B4
#undef VMW
#undef LDB4
#undef LDA4
#undef MFMA16_4
#undef PH_MID
#undef PH_END

  // epilogue: f32 C write, per wave 64x64 block
  const int cr = (lane >> 4) * 4;
  const int cc = lane & 15;
  #pragma unroll
  for (int f = 0; f < 4; ++f)
    #pragma unroll
    for (int n = 0; n < 4; ++n)
      #pragma unroll
      for (int r = 0; r < 4; ++r) {
        const int row = bm + wrow + f * 16 + cr + r;
        const int col = bn + wcol + n * 16 + cc;
        C[(size_t)row * 2048 + col] = acc[f][n][r];
      }
}

// ---------------------------------------------------------------------------
// 5) per-head RMSNorm(qk_w) + RoPE on q,k in place; q scaled by QSCALE.
//    Vectorized (R8): bf16x8 per lane, rotation lane-local, 3 shuffles per
//    8 elements, float4 table loads.
// ---------------------------------------------------------------------------
__global__ __launch_bounds__(256) void qk_rope_kernel(
    unsigned short* __restrict__ QKV, const float* __restrict__ rope,
    const float* __restrict__ qk_w)
{
  const int tid  = threadIdx.x;
  const int lane = tid & 63;
  const int task = blockIdx.x * 4 + (tid >> 6);   // 0..16383 = bl*4 + hg
  const int hg   = task & 3;                      // head group (8 heads)
  const int bl   = task >> 2;                     // b*2048 + l
  const int l    = bl & 2047;
  const int h    = hg * 8 + (lane >> 3);
  const int d0   = (lane & 7) * 8;
  const size_t base = (size_t)bl * 6144 + h * 64 + d0;

  // rope + weight for this lane's 8 dims (f32, coalesced float4 pairs)
  float r0[8], r1[8], wv[8];
  {
    const float4* p0 = (const float4*)(rope + l * 64 + d0);
    const float4* p1 = (const float4*)(rope + 131072 + l * 64 + d0);
    const float4* pw = (const float4*)(qk_w + d0);
    float4 a, b2;
    a = p0[0]; b2 = p0[1];
    r0[0]=a.x; r0[1]=a.y; r0[2]=a.z; r0[3]=a.w; r0[4]=b2.x; r0[5]=b2.y; r0[6]=b2.z; r0[7]=b2.w;
    a = p1[0]; b2 = p1[1];
    r1[0]=a.x; r1[1]=a.y; r1[2]=a.z; r1[3]=a.w; r1[4]=b2.x; r1[5]=b2.y; r1[6]=b2.z; r1[7]=b2.w;
    a = pw[0]; b2 = pw[1];
    wv[0]=a.x; wv[1]=a.y; wv[2]=a.z; wv[3]=a.w; wv[4]=b2.x; wv[5]=b2.y; wv[6]=b2.z; wv[7]=b2.w;
  }

  #pragma unroll
  for (int t = 0; t < 2; ++t) {        // t=0: q, t=1: k
    unsigned short* p = &QKV[base + (size_t)2048 * t];
    const uint4 raw = *(const uint4*)p;
    const unsigned int* u = (const unsigned int*)&raw;
    float v[8];
    #pragma unroll
    for (int j = 0; j < 4; ++j) {
      v[2*j]   = bf2f(u[j]);
      v[2*j+1] = bf2f_hi(u[j]);
    }
    float sq = v[0]*v[0] + v[1]*v[1] + v[2]*v[2] + v[3]*v[3]
             + v[4]*v[4] + v[5]*v[5] + v[6]*v[6] + v[7]*v[7];
    sq += __shfl_xor(sq, 1);
    sq += __shfl_xor(sq, 2);
    sq += __shfl_xor(sq, 4);           // sum over the 8 lanes of this row
    const float rn = rsqrtf(sq * (1.f / 64.f) + EPS_F32)
                   * ((t == 0) ? QSCALE : 1.0f);
    float vn[8];
    #pragma unroll
    for (int j = 0; j < 8; ++j) vn[j] = v[j] * (rn * wv[j]);
    unsigned int pk[4];
    #pragma unroll
    for (int j = 0; j < 4; ++j) {      // pair (2j, 2j+1): x_hat = (-x1, x0)
      const float o0 = vn[2*j]   * r0[2*j]   - vn[2*j+1] * r1[2*j];
      const float o1 = vn[2*j+1] * r0[2*j+1] + vn[2*j]   * r1[2*j+1];
      pk[j] = (unsigned int)f2bf(o0) | ((unsigned int)f2bf(o1) << 16);
    }
    *(uint4*)p = make_uint4(pk[0], pk[1], pk[2], pk[3]);
  }
}

// ---------------------------------------------------------------------------
// 6) MFMA flash attention (no-max softmax). 64q/wave, 256q/block, k-tile 64.
//    (verified R4 structure: plain two-barrier staging, no prefetch/setprio)
// ---------------------------------------------------------------------------
__global__ __launch_bounds__(256, 2) void attn_mfma_kernel(
    const unsigned short* __restrict__ QKV,  // [4096][6144] (q,k roped)
    const unsigned short* __restrict__ Vt,   // [64 bh][64 d][2048 k-perm]
    unsigned short* __restrict__ O)          // [4096][2048]
{
  __shared__ unsigned short Ks[64 * 72];
  __shared__ unsigned short Vs[64 * 72];
  __shared__ unsigned short Ps[4 * 64 * 68];
  const int tid  = threadIdx.x;
  const int lane = tid & 63;
  const int wave = tid >> 6;
  const int blk = blockIdx.x;              // 0..511
  const int bh = blk & 63;                 // blk%8 == bh%8 -> XCD-affine
  const int qt = blk >> 6;                 // 0..7
  const int b = bh >> 5, h = bh & 31;
  const int rowbase = b << 11;
  const int qbase = qt * 256 + wave * 64;  // 64 q rows per wave

  const int m16  = lane & 15;
  const int quad = lane >> 4;
  const int m32  = lane & 31;
  const int hl   = lane >> 5;

  // Q fragments (already scaled by QSCALE in rope kernel): 4 x 16-row tiles
  bf16x8 qf[4][2];
  #pragma unroll
  for (int qi = 0; qi < 4; ++qi)
    #pragma unroll
    for (int ch = 0; ch < 2; ++ch)
      qf[qi][ch] = *(const bf16x8*)&QKV[(size_t)(rowbase + qbase + qi * 16 + m16) * 6144
                                        + h * 64 + ch * 32 + quad * 8];

  const int sr = tid >> 2;            // staging row 0..63
  const int sc = (tid & 3) * 16;      // staging col (shorts)
  const unsigned short* Kg = QKV + (size_t)(rowbase + sr) * 6144 + 2048 + h * 64 + sc;
  const unsigned short* Vg = Vt + (size_t)(bh * 64 + sr) * 2048 + sc;

  f32x16 accO[2][2] = {};                 // [q-subtile 32][d-tile 32]
  float part[4][4] = {};                  // per-16-row-tile row sums
  unsigned short* Pw = &Ps[(wave * 64) * 68];

  for (int kt = 0; kt < 32; ++kt) {
    __syncthreads();
    {
      const uint4* kp = (const uint4*)(Kg + (size_t)kt * 64 * 6144);
      const uint4* vp = (const uint4*)(Vg + kt * 64);
      uint4 k0 = kp[0], k1 = kp[1];
      uint4 v0 = vp[0], v1 = vp[1];
      *(uint4*)&Ks[sr * 72 + sc]     = k0;
      *(uint4*)&Ks[sr * 72 + sc + 8] = k1;
      *(uint4*)&Vs[sr * 72 + sc]     = v0;
      *(uint4*)&Vs[sr * 72 + sc + 8] = v1;
    }
    __syncthreads();

    // S (16x16x32) -> exp2 -> pack P (key perm p = c*4 + kj)
    unsigned int pk[4][4][2];
    #pragma unroll
    for (int kj = 0; kj < 4; ++kj) {
      bf16x8 kf0 = *(const bf16x8*)&Ks[(kj * 16 + m16) * 72 + quad * 8];
      bf16x8 kf1 = *(const bf16x8*)&Ks[(kj * 16 + m16) * 72 + 32 + quad * 8];
      #pragma unroll
      for (int qi = 0; qi < 4; ++qi) {
        f32x4 acc = {};
        acc = __builtin_amdgcn_mfma_f32_16x16x32_bf16(qf[qi][0], kf0, acc, 0, 0, 0);
        acc = __builtin_amdgcn_mfma_f32_16x16x32_bf16(qf[qi][1], kf1, acc, 0, 0, 0);
        #pragma unroll
        for (int r = 0; r < 4; ++r) {
          float p = EXP2F(acc[r]);
          part[qi][r] += p;
          unsigned int pb = f2bf_rn_u(p);
          if (kj == 0)      pk[qi][r][0]  = pb >> 16;
          else if (kj == 1) pk[qi][r][0] |= pb & 0xffff0000u;
          else if (kj == 2) pk[qi][r][1]  = pb >> 16;
          else              pk[qi][r][1] |= pb & 0xffff0000u;
        }
      }
    }
    #pragma unroll
    for (int qi = 0; qi < 4; ++qi)
      #pragma unroll
      for (int r = 0; r < 4; ++r)
        *(uint2*)&Pw[(qi * 16 + quad * 4 + r) * 68 + m16 * 4] =
            make_uint2(pk[qi][r][0], pk[qi][r][1]);
    // wave-private P region: RAW covered by lgkmcnt, no barrier

    // PV (32x32x16): accO[qs][dt], vb reused across qs
    #pragma unroll
    for (int ch = 0; ch < 4; ++ch) {
      bf16x8 pa0 = *(const bf16x8*)&Pw[m32 * 68 + ch * 16 + hl * 8];
      bf16x8 pa1 = *(const bf16x8*)&Pw[(32 + m32) * 68 + ch * 16 + hl * 8];
      bf16x8 vb0 = *(const bf16x8*)&Vs[m32 * 72 + ch * 16 + hl * 8];
      bf16x8 vb1 = *(const bf16x8*)&Vs[(32 + m32) * 72 + ch * 16 + hl * 8];
      accO[0][0] = __builtin_amdgcn_mfma_f32_32x32x16_bf16(pa0, vb0, accO[0][0], 0, 0, 0);
      accO[0][1] = __builtin_amdgcn_mfma_f32_32x32x16_bf16(pa0, vb1, accO[0][1], 0, 0, 0);
      accO[1][0] = __builtin_amdgcn_mfma_f32_32x32x16_bf16(pa1, vb0, accO[1][0], 0, 0, 0);
      accO[1][1] = __builtin_amdgcn_mfma_f32_32x32x16_bf16(pa1, vb1, accO[1][1], 0, 0, 0);
    }
  }

  // reduce row sums over the 16 n-lanes
  #pragma unroll
  for (int qi = 0; qi < 4; ++qi)
    #pragma unroll
    for (int r = 0; r < 4; ++r)
      #pragma unroll
      for (int off = 1; off < 16; off <<= 1)
        part[qi][r] += __shfl_xor(part[qi][r], off);

  // epilogue: per 32-row q-subtile, gather row sum, divide, store
  #pragma unroll
  for (int qs = 0; qs < 2; ++qs) {
    #pragma unroll
    for (int reg = 0; reg < 16; ++reg) {
      const int r = reg & 3;
      const int s = reg >> 2;
      const int qsrc = ((2 * s + hl) & 3) * 16 + m16;
      const float rs = __shfl(part[qs * 2 + (reg >> 3)][r], qsrc);
      const float inv = RCPF(rs);
      const int rho = r + 8 * s + 4 * hl;      // row in 32x32 C layout
      const size_t base = (size_t)(rowbase + qbase + qs * 32 + rho) * 2048 + h * 64;
      O[base + m32]      = f2bf(accO[qs][0][reg] * inv);
      O[base + 32 + m32] = f2bf(accO[qs][1][reg] * inv);
    }
  }
}

// ---------------------------------------------------------------------------
// launch
// ---------------------------------------------------------------------------
extern "C" void kernel_launch(void* const* d_in, const int* in_sizes, int n_in,
                              void* d_out, int out_size, void* d_ws, size_t ws_size,
                              hipStream_t stream) {
  (void)in_sizes; (void)n_in; (void)out_size; (void)ws_size;
  const float* x     = (const float*)d_in[0];
  const float* cond  = (const float*)d_in[1];
  const float* rope  = (const float*)d_in[2];
  const float* w_ada = (const float*)d_in[3];
  const float* w_qkv = (const float*)d_in[4];
  const float* w_out = (const float*)d_in[5];
  const float* qk_w  = (const float*)d_in[6];
  float* out = (float*)d_out;

  char* ws = (char*)d_ws;
  float*          ss   = (float*)ws;                       // 32 KB
  unsigned short* H    = (unsigned short*)(ws + 32768);    // 16 MB, reused as O
  unsigned short* Wq   = H + 8388608;                      // 24 MB
  unsigned short* Wo   = Wq + 12582912;                    // 8 MB  (contiguous after Wq)
  unsigned short* QKV  = Wo + 4194304;                     // 48 MB (q,k used)
  unsigned short* Vt_g = QKV + 25165824;                   // 16 MB

  // ada GEMM (blocks 0..2047) + weight cast (blocks 2048..18431), merged
  prep_kernel<<<18432, 256, 0, stream>>>(cond, w_ada, ss, w_qkv, w_out, Wq);
  ada_rms_kernel<<<4096, 256, 0, stream>>>(x, ss, H);
  // q,k = H @ w_qkv[0:4096]^T -> QKV cols 0..4095 (grid 256 = 1 full round)
  gemm_qk_8p<<<256, 512, 0, stream>>>(H, Wq, QKV);
  // v = H @ w_qkv[4096:6144]^T -> Vt (transposed + k-permuted), grid 256
  gemm_v_4p<<<256, 512, 0, stream>>>(H, Wq + (size_t)4096 * 2048, Vt_g);
  qk_rope_kernel<<<4096, 256, 0, stream>>>(QKV, rope, qk_w);
  attn_mfma_kernel<<<512, 256, 0, stream>>>(QKV, Vt_g, H);
  gemm_out_4p<<<256, 512, 0, stream>>>(H, Wo, out);
}